// Round 5
// baseline (395.772 us; speedup 1.0000x reference)
//
#include <hip/hip_runtime.h>
#include <hip/hip_bf16.h>

// PAM module R5: q/k/v 1x1 projections -> bf16 MFMA attention -> gamma*out + x.
// R4 post-mortem: removing LDS staging also removed the 1-iter-ahead prefetch;
// raw L2 latency sat in the per-iter dependency chain at 2 waves/SIMD (grid-capped).
// R5: same barrier-free main loop, but K/V fragments are PING-PONG DOUBLE-BUFFERED
// IN REGISTERS -- loads for tile it+1 issue before compute of tile it, consumed a
// full iteration later. Zero LDS / zero barriers in the loop; LDS only for the
// final O-reduction + epilogue.
//
// Workspace layouts (bf16, chunk = 64 lanes x 16B = 1KB, frag-major):
//   qf_ws[b][strip64][ni][kc][lane]           8MB
//   kt   [b][tile128][mb][kc][lane]           8MB  (mb = m-block 0..7)
//   vt   [b][tile128][cb*16+wq][l16]{8}       8MB  (wq = w*4+quad)

typedef __bf16 v8bf __attribute__((ext_vector_type(8)));
typedef float  v4f  __attribute__((ext_vector_type(4)));

#define B_ 8
#define C_ 128
#define N_ 4096

static __device__ __forceinline__ unsigned short f2bf_rne(float f) {
    union { float f; unsigned u; } v; v.f = f;
    return (unsigned short)((v.u + 0x7fffu + ((v.u >> 16) & 1u)) >> 16);
}
static __device__ __forceinline__ unsigned fbits(float f) {
    union { float f; unsigned u; } v; v.f = f; return v.u;
}

// ---------------------------------------------------------------------------
// Kernel 1: one block per (projection pp, tile t, batch b). 256 thr / 4 waves.
// W = pw*diag(dw) folded to bf16. GEMM 128x128x128 via 16x16x32 MFMA.
// Result bounced through LDS scratch then copied out coalesced, frag-major.
// (Unchanged from R4 -- isolating the attn variable this round.)
// ---------------------------------------------------------------------------
__global__ __launch_bounds__(256, 2) void proj_kernel(
    const float* __restrict__ x,
    const float* __restrict__ dw_q, const float* __restrict__ pw_q,
    const float* __restrict__ dw_k, const float* __restrict__ pw_k,
    const float* __restrict__ dw_v, const float* __restrict__ pw_v,
    unsigned short* __restrict__ qf_ws, unsigned short* __restrict__ kt,
    unsigned short* __restrict__ vt)
{
    __shared__ unsigned short xT[128 * 136];  // xT[n][c]
    __shared__ unsigned short Ws[128 * 136];  // W[o][c]; reused as store scratch

    const int bid = blockIdx.x;
    const int bb  = bid & 7;
    const int t   = (bid >> 3) & 31;
    const int pp  = bid >> 8;            // 0:q 1:k 2:v
    const int n0  = t * 128;
    const int tid = threadIdx.x;
    const int w    = tid >> 6;
    const int lane = tid & 63;
    const int quad = lane >> 4;
    const int l16  = lane & 15;

    // ---- stage xT[n][c] (transpose + cvt bf16); float4 reads along n
    #pragma unroll
    for (int k = 0; k < 16; ++k) {
        const int idx = tid + k * 256;          // 4096 float4
        const int c  = idx >> 5;
        const int nq = idx & 31;
        float4 f = *(const float4*)(x + ((size_t)(bb * C_ + c)) * N_ + n0 + nq * 4);
        xT[(nq * 4 + 0) * 136 + c] = f2bf_rne(f.x);
        xT[(nq * 4 + 1) * 136 + c] = f2bf_rne(f.y);
        xT[(nq * 4 + 2) * 136 + c] = f2bf_rne(f.z);
        xT[(nq * 4 + 3) * 136 + c] = f2bf_rne(f.w);
    }
    // ---- stage Ws[o][c] = pw[o][c]*dw[c], bf16
    const float* pw = (pp == 0) ? pw_q : (pp == 1) ? pw_k : pw_v;
    const float* dw = (pp == 0) ? dw_q : (pp == 1) ? dw_k : dw_v;
    #pragma unroll
    for (int k = 0; k < 16; ++k) {
        const int idx = tid + k * 256;
        const int o  = idx >> 5;
        const int c4 = (idx & 31) * 4;
        float4 p4 = *(const float4*)(pw + o * 128 + c4);
        float4 d4 = *(const float4*)(dw + c4);
        unsigned lo = (unsigned)f2bf_rne(p4.x * d4.x) | ((unsigned)f2bf_rne(p4.y * d4.y) << 16);
        unsigned hi = (unsigned)f2bf_rne(p4.z * d4.z) | ((unsigned)f2bf_rne(p4.w * d4.w) << 16);
        *(unsigned long long*)&Ws[o * 136 + c4] =
            (unsigned long long)lo | ((unsigned long long)hi << 32);
    }
    __syncthreads();

    // q/k: D[n|m][o] = xT(A rows) * Ws(B cols);  v: D[o][m] = Ws(A rows) * xT(B cols)
    const unsigned short* As = (pp < 2) ? xT : Ws;
    const unsigned short* Bs = (pp < 2) ? Ws : xT;

    v4f acc[2][8];   // [mi][cb]: rows = w*32 + mi*16, cols = cb*16
    #pragma unroll
    for (int i = 0; i < 2; ++i)
        #pragma unroll
        for (int j = 0; j < 8; ++j)
            acc[i][j] = (v4f){0.f, 0.f, 0.f, 0.f};

    #pragma unroll
    for (int kc = 0; kc < 4; ++kc) {
        v8bf av[2];
        #pragma unroll
        for (int i = 0; i < 2; ++i)
            av[i] = *(const v8bf*)&As[(w * 32 + i * 16 + l16) * 136 + kc * 32 + quad * 8];
        #pragma unroll
        for (int cb = 0; cb < 8; ++cb) {
            v8bf bv = *(const v8bf*)&Bs[(cb * 16 + l16) * 136 + kc * 32 + quad * 8];
            acc[0][cb] = __builtin_amdgcn_mfma_f32_16x16x32_bf16(av[0], bv, acc[0][cb], 0, 0, 0);
            acc[1][cb] = __builtin_amdgcn_mfma_f32_16x16x32_bf16(av[1], bv, acc[1][cb], 0, 0, 0);
        }
    }
    __syncthreads();   // done reading xT/Ws; Ws becomes scratch

    // ---- D-layout -> plain scratch [row][136]
    unsigned short* sc = Ws;
    #pragma unroll
    for (int mi = 0; mi < 2; ++mi)
        #pragma unroll
        for (int cb = 0; cb < 8; ++cb)
            #pragma unroll
            for (int r = 0; r < 4; ++r)
                sc[(w * 32 + mi * 16 + quad * 4 + r) * 136 + cb * 16 + l16] =
                    f2bf_rne(acc[mi][cb][r]);
    __syncthreads();

    // ---- coalesced fragment-major global copy (8 passes x 4KB)
    if (pp == 0) {
        unsigned short* dst = qf_ws + ((size_t)(bb * 64 + t * 2)) * 8192;
        #pragma unroll
        for (int p = 0; p < 8; ++p) {
            const int g     = p * 4 + w;
            const int strip = g >> 4, ni = (g >> 2) & 3, kc = g & 3;
            *(uint4*)(dst + ((size_t)g * 64 + lane) * 8) =
                *(const uint4*)&sc[(strip * 64 + ni * 16 + l16) * 136 + kc * 32 + quad * 8];
        }
    } else if (pp == 1) {
        unsigned short* dst = kt + ((size_t)(bb * 32 + t)) * 16384;
        #pragma unroll
        for (int p = 0; p < 8; ++p) {
            const int g  = p * 4 + w;
            const int mb = g >> 2, kc = g & 3;
            *(uint4*)(dst + ((size_t)g * 64 + lane) * 8) =
                *(const uint4*)&sc[(mb * 16 + l16) * 136 + kc * 32 + quad * 8];
        }
    } else {
        unsigned short* dst = vt + ((size_t)(bb * 32 + t)) * 16384;
        #pragma unroll
        for (int p = 0; p < 8; ++p) {
            const int d  = p * 256 + tid;
            const int cb = d >> 8, wq = (d >> 4) & 15, l = d & 15;
            *(uint4*)(dst + (size_t)d * 8) =
                *(const uint4*)&sc[(cb * 16 + l) * 136 + wq * 8];
        }
    }
}

// ---------------------------------------------------------------------------
// Kernel 2: attention. grid 512 = (b = bid&7, 64-row n-strip = bid>>3).
// 256 thr / 4 waves; wave = m-quarter, full c=128, full n=64. Main loop:
// register ping-pong double-buffered K/V fragment loads (1KB coalesced),
// S^T = K^T Q, exp, bpermute C->B-frag, O += V*P. No LDS / no barriers.
// ---------------------------------------------------------------------------
__global__ __launch_bounds__(256, 2) void attn_kernel(
    const unsigned short* __restrict__ qf_ws, const unsigned short* __restrict__ kt,
    const unsigned short* __restrict__ vt, const float* __restrict__ x,
    const float* __restrict__ gamma, float* __restrict__ out)
{
    __shared__ float red[64 * 132];   // O reduction scratch [n][c] (+pad)
    __shared__ float l_s[4][64];

    const int bid = blockIdx.x;
    const int bb  = bid & 7;
    const int s   = bid >> 3;        // n-strip 0..63
    const int n0  = s * 64;
    const int tid = threadIdx.x;
    const int w    = tid >> 6;       // wave = m-quarter owner
    const int lane = tid & 63;
    const int quad = lane >> 4;
    const int l16  = lane & 15;

    // ---- Q fragments, iteration-invariant (B-operand of S^T)
    v8bf qf[4][4];
    {
        const unsigned short* qb = qf_ws + ((size_t)(bb * 64 + s)) * 8192;
        #pragma unroll
        for (int ni = 0; ni < 4; ++ni)
            #pragma unroll
            for (int kc = 0; kc < 4; ++kc)
                qf[ni][kc] = *(const v8bf*)(qb + ((size_t)(ni * 4 + kc) * 64 + lane) * 8);
    }

    v4f oacc[8][4];  // [cb][ni] partial O over this wave's 32-m subset
    #pragma unroll
    for (int i = 0; i < 8; ++i)
        #pragma unroll
        for (int j = 0; j < 4; ++j)
            oacc[i][j] = (v4f){0.f, 0.f, 0.f, 0.f};
    float lpart[4] = {0.f, 0.f, 0.f, 0.f};

    const int la = ((((quad & 1) << 1) << 4) + l16) << 2;  // bpermute byte idx
    const int lb = la + 64;

    const unsigned short* kbase = kt + ((size_t)(bb * 32)) * 16384 + ((size_t)(w * 8) * 64 + lane) * 8;
    const unsigned short* vbase = vt + ((size_t)(bb * 32)) * 16384 + ((size_t)(w * 64 + lane)) * 8;

    // ---- register ping-pong buffers
    v8bf kfA[2][4], vfA[8], kfB[2][4], vfB[8];

    auto loadK = [&](v8bf (*kf)[4], int tile) {
        const unsigned short* kp = kbase + (size_t)tile * 16384;
        #pragma unroll
        for (int mi = 0; mi < 2; ++mi)
            #pragma unroll
            for (int kc = 0; kc < 4; ++kc)
                kf[mi][kc] = *(const v8bf*)(kp + (size_t)((mi * 4 + kc) * 64) * 8);
    };
    auto loadV = [&](v8bf* vf, int tile) {
        const unsigned short* vp = vbase + (size_t)tile * 16384;
        #pragma unroll
        for (int cb = 0; cb < 8; ++cb)
            vf[cb] = *(const v8bf*)(vp + (size_t)(cb * 256) * 8);
    };

    auto compute = [&](v8bf (*kfr)[4], v8bf* vfr) {
        // ---- S^T (m-quarter x n64)
        v4f sacc[2][4];
        #pragma unroll
        for (int mi = 0; mi < 2; ++mi)
            #pragma unroll
            for (int ni = 0; ni < 4; ++ni) sacc[mi][ni] = (v4f){0.f, 0.f, 0.f, 0.f};
        #pragma unroll
        for (int mi = 0; mi < 2; ++mi)
            #pragma unroll
            for (int kc = 0; kc < 4; ++kc)
                #pragma unroll
                for (int ni = 0; ni < 4; ++ni)
                    sacc[mi][ni] = __builtin_amdgcn_mfma_f32_16x16x32_bf16(
                        kfr[mi][kc], qf[ni][kc], sacc[mi][ni], 0, 0, 0);

        // ---- exp + pack (v_perm: one instr per bf16 pair)
        unsigned pk_[2][4][2];
        #pragma unroll
        for (int mi = 0; mi < 2; ++mi)
            #pragma unroll
            for (int ni = 0; ni < 4; ++ni) {
                float e0 = __expf(sacc[mi][ni][0]), e1 = __expf(sacc[mi][ni][1]);
                float e2 = __expf(sacc[mi][ni][2]), e3 = __expf(sacc[mi][ni][3]);
                lpart[ni] += (e0 + e1) + (e2 + e3);
                pk_[mi][ni][0] = __builtin_amdgcn_perm(fbits(e1), fbits(e0), 0x07060302);
                pk_[mi][ni][1] = __builtin_amdgcn_perm(fbits(e3), fbits(e2), 0x07060302);
            }

        // ---- C-layout -> B-frag via bpermute (R3-proven mapping)
        v8bf pf[4];
        #pragma unroll
        for (int ni = 0; ni < 4; ++ni) {
            unsigned sLo = (quad < 2) ? pk_[0][ni][0] : pk_[1][ni][0];
            unsigned sHi = (quad < 2) ? pk_[0][ni][1] : pk_[1][ni][1];
            union { unsigned u[4]; v8bf v; } pu;
            pu.u[0] = (unsigned)__builtin_amdgcn_ds_bpermute(la, (int)sLo);
            pu.u[1] = (unsigned)__builtin_amdgcn_ds_bpermute(la, (int)sHi);
            pu.u[2] = (unsigned)__builtin_amdgcn_ds_bpermute(lb, (int)sLo);
            pu.u[3] = (unsigned)__builtin_amdgcn_ds_bpermute(lb, (int)sHi);
            pf[ni] = pu.v;
        }

        // ---- O[c][n] += V * P
        #pragma unroll
        for (int cb = 0; cb < 8; ++cb) {
            #pragma unroll
            for (int ni = 0; ni < 4; ++ni)
                oacc[cb][ni] = __builtin_amdgcn_mfma_f32_16x16x32_bf16(
                    vfr[cb], pf[ni], oacc[cb][ni], 0, 0, 0);
        }
    };

    loadK(kfA, 0); loadV(vfA, 0);
    for (int it = 0; it < 32; it += 2) {
        loadK(kfB, it + 1);          loadV(vfB, it + 1);
        compute(kfA, vfA);
        loadK(kfA, (it + 2) & 31);   loadV(vfA, (it + 2) & 31);
        compute(kfB, vfB);
    }

    // ---- softmax denominators (per-wave partials over its 32-m subset)
    #pragma unroll
    for (int ni = 0; ni < 4; ++ni) {
        float r = lpart[ni];
        r += __shfl_xor(r, 16);
        r += __shfl_xor(r, 32);
        if (lane < 16) l_s[w][ni * 16 + lane] = r;
    }

    // ---- O reduction across the 4 m-quarter waves
    for (int rw = 0; rw < 4; ++rw) {
        if (w == rw) {
            #pragma unroll
            for (int cb = 0; cb < 8; ++cb)
                #pragma unroll
                for (int ni = 0; ni < 4; ++ni) {
                    float* p = &red[(ni * 16 + l16) * 132 + cb * 16 + quad * 4];
                    if (rw == 0) *(v4f*)p = oacc[cb][ni];
                    else {
                        v4f tv = *(const v4f*)p;
                        tv += oacc[cb][ni];
                        *(v4f*)p = tv;
                    }
                }
        }
        __syncthreads();
    }

    // ---- epilogue: out = gamma * O / l + x   (lane = n, coalesced)
    const float g = gamma[0];
    const float li = 1.0f / (((l_s[0][lane] + l_s[1][lane]) + (l_s[2][lane] + l_s[3][lane])));
    #pragma unroll
    for (int ci = 0; ci < 32; ++ci) {
        const int c = w * 32 + ci;
        const size_t idx = ((size_t)(bb * C_ + c)) * N_ + n0 + lane;
        out[idx] = g * red[lane * 132 + c] * li + x[idx];
    }
}

// ---------------------------------------------------------------------------
extern "C" void kernel_launch(void* const* d_in, const int* in_sizes, int n_in,
                              void* d_out, int out_size, void* d_ws, size_t ws_size,
                              hipStream_t stream)
{
    (void)in_sizes; (void)n_in; (void)out_size; (void)ws_size;
    const float* x     = (const float*)d_in[0];
    const float* dw_q  = (const float*)d_in[1];
    const float* pw_q  = (const float*)d_in[2];
    const float* dw_k  = (const float*)d_in[3];
    const float* pw_k  = (const float*)d_in[4];
    const float* dw_v  = (const float*)d_in[5];
    const float* pw_v  = (const float*)d_in[6];
    const float* gamma = (const float*)d_in[7];
    float* out = (float*)d_out;

    unsigned short* qf_ws = (unsigned short*)d_ws;                  // 8 MB
    unsigned short* kt    = qf_ws + (size_t)B_ * N_ * C_;           // 8 MB
    unsigned short* vt    = kt    + (size_t)B_ * N_ * C_;           // 8 MB

    proj_kernel<<<dim3(768), dim3(256), 0, stream>>>(
        x, dw_q, pw_q, dw_k, pw_k, dw_v, pw_v, qf_ws, kt, vt);
    attn_kernel<<<dim3(512), dim3(256), 0, stream>>>(
        qf_ws, kt, vt, x, gamma, out);
}

// Round 6
// 181.803 us; speedup vs baseline: 2.1769x; 2.1769x over previous
//
#include <hip/hip_runtime.h>
#include <hip/hip_bf16.h>

// PAM module R6: q/k/v 1x1 projections -> bf16 MFMA attention -> gamma*out + x.
// R5 post-mortem: lambda pointer-to-register-array + 390-reg footprint => scratch
// spill (WRITE_SIZE 772MB). R6 shrinks per-wave state so the pipeline FITS in the
// 256-reg/wave budget (2 waves/SIMD): n-strip 64->32 (grid 1024), so qf=32,
// oacc=64(AGPR); K is register ping-pong double-buffered (2x32), V single-buffered
// (loaded right after consumption, hidden by next iter's S+exp+bpermute phase).
// No lambdas / no array pointers -- macro-expanded compute. Zero LDS / zero
// barriers in the main loop.
//
// Workspace layouts (bf16, chunk = 64 lanes x 16B = 1KB, frag-major):
//   qf_ws[b][strip32][ni2][kc4][lane]         8MB  (same bytes as R4 layout)
//   kt   [b][tile128][mb8][kc4][lane]         8MB
//   vt   [b][tile128][cb*16+wq][l16]{8}       8MB

typedef __bf16 v8bf __attribute__((ext_vector_type(8)));
typedef float  v4f  __attribute__((ext_vector_type(4)));

#define B_ 8
#define C_ 128
#define N_ 4096

static __device__ __forceinline__ unsigned short f2bf_rne(float f) {
    union { float f; unsigned u; } v; v.f = f;
    return (unsigned short)((v.u + 0x7fffu + ((v.u >> 16) & 1u)) >> 16);
}
static __device__ __forceinline__ unsigned fbits(float f) {
    union { float f; unsigned u; } v; v.f = f; return v.u;
}

// ---------------------------------------------------------------------------
// Kernel 1: unchanged from R4 (proven correct; isolating the attn variable).
// ---------------------------------------------------------------------------
__global__ __launch_bounds__(256, 2) void proj_kernel(
    const float* __restrict__ x,
    const float* __restrict__ dw_q, const float* __restrict__ pw_q,
    const float* __restrict__ dw_k, const float* __restrict__ pw_k,
    const float* __restrict__ dw_v, const float* __restrict__ pw_v,
    unsigned short* __restrict__ qf_ws, unsigned short* __restrict__ kt,
    unsigned short* __restrict__ vt)
{
    __shared__ unsigned short xT[128 * 136];  // xT[n][c]
    __shared__ unsigned short Ws[128 * 136];  // W[o][c]; reused as store scratch

    const int bid = blockIdx.x;
    const int bb  = bid & 7;
    const int t   = (bid >> 3) & 31;
    const int pp  = bid >> 8;            // 0:q 1:k 2:v
    const int n0  = t * 128;
    const int tid = threadIdx.x;
    const int w    = tid >> 6;
    const int lane = tid & 63;
    const int quad = lane >> 4;
    const int l16  = lane & 15;

    #pragma unroll
    for (int k = 0; k < 16; ++k) {
        const int idx = tid + k * 256;
        const int c  = idx >> 5;
        const int nq = idx & 31;
        float4 f = *(const float4*)(x + ((size_t)(bb * C_ + c)) * N_ + n0 + nq * 4);
        xT[(nq * 4 + 0) * 136 + c] = f2bf_rne(f.x);
        xT[(nq * 4 + 1) * 136 + c] = f2bf_rne(f.y);
        xT[(nq * 4 + 2) * 136 + c] = f2bf_rne(f.z);
        xT[(nq * 4 + 3) * 136 + c] = f2bf_rne(f.w);
    }
    const float* pw = (pp == 0) ? pw_q : (pp == 1) ? pw_k : pw_v;
    const float* dw = (pp == 0) ? dw_q : (pp == 1) ? dw_k : dw_v;
    #pragma unroll
    for (int k = 0; k < 16; ++k) {
        const int idx = tid + k * 256;
        const int o  = idx >> 5;
        const int c4 = (idx & 31) * 4;
        float4 p4 = *(const float4*)(pw + o * 128 + c4);
        float4 d4 = *(const float4*)(dw + c4);
        unsigned lo = (unsigned)f2bf_rne(p4.x * d4.x) | ((unsigned)f2bf_rne(p4.y * d4.y) << 16);
        unsigned hi = (unsigned)f2bf_rne(p4.z * d4.z) | ((unsigned)f2bf_rne(p4.w * d4.w) << 16);
        *(unsigned long long*)&Ws[o * 136 + c4] =
            (unsigned long long)lo | ((unsigned long long)hi << 32);
    }
    __syncthreads();

    const unsigned short* As = (pp < 2) ? xT : Ws;
    const unsigned short* Bs = (pp < 2) ? Ws : xT;

    v4f acc[2][8];
    #pragma unroll
    for (int i = 0; i < 2; ++i)
        #pragma unroll
        for (int j = 0; j < 8; ++j)
            acc[i][j] = (v4f){0.f, 0.f, 0.f, 0.f};

    #pragma unroll
    for (int kc = 0; kc < 4; ++kc) {
        v8bf av[2];
        #pragma unroll
        for (int i = 0; i < 2; ++i)
            av[i] = *(const v8bf*)&As[(w * 32 + i * 16 + l16) * 136 + kc * 32 + quad * 8];
        #pragma unroll
        for (int cb = 0; cb < 8; ++cb) {
            v8bf bv = *(const v8bf*)&Bs[(cb * 16 + l16) * 136 + kc * 32 + quad * 8];
            acc[0][cb] = __builtin_amdgcn_mfma_f32_16x16x32_bf16(av[0], bv, acc[0][cb], 0, 0, 0);
            acc[1][cb] = __builtin_amdgcn_mfma_f32_16x16x32_bf16(av[1], bv, acc[1][cb], 0, 0, 0);
        }
    }
    __syncthreads();

    unsigned short* sc = Ws;
    #pragma unroll
    for (int mi = 0; mi < 2; ++mi)
        #pragma unroll
        for (int cb = 0; cb < 8; ++cb)
            #pragma unroll
            for (int r = 0; r < 4; ++r)
                sc[(w * 32 + mi * 16 + quad * 4 + r) * 136 + cb * 16 + l16] =
                    f2bf_rne(acc[mi][cb][r]);
    __syncthreads();

    if (pp == 0) {
        unsigned short* dst = qf_ws + ((size_t)(bb * 64 + t * 2)) * 8192;
        #pragma unroll
        for (int p = 0; p < 8; ++p) {
            const int g     = p * 4 + w;
            const int strip = g >> 4, ni = (g >> 2) & 3, kc = g & 3;
            *(uint4*)(dst + ((size_t)g * 64 + lane) * 8) =
                *(const uint4*)&sc[(strip * 64 + ni * 16 + l16) * 136 + kc * 32 + quad * 8];
        }
    } else if (pp == 1) {
        unsigned short* dst = kt + ((size_t)(bb * 32 + t)) * 16384;
        #pragma unroll
        for (int p = 0; p < 8; ++p) {
            const int g  = p * 4 + w;
            const int mb = g >> 2, kc = g & 3;
            *(uint4*)(dst + ((size_t)g * 64 + lane) * 8) =
                *(const uint4*)&sc[(mb * 16 + l16) * 136 + kc * 32 + quad * 8];
        }
    } else {
        unsigned short* dst = vt + ((size_t)(bb * 32 + t)) * 16384;
        #pragma unroll
        for (int p = 0; p < 8; ++p) {
            const int d  = p * 256 + tid;
            const int cb = d >> 8, wq = (d >> 4) & 15, l = d & 15;
            *(uint4*)(dst + (size_t)d * 8) =
                *(const uint4*)&sc[(cb * 16 + l) * 136 + wq * 8];
        }
    }
}

// ---------------------------------------------------------------------------
// Kernel 2: attention. grid 1024 = (b = bid&7, 32-row n-strip = bid>>3).
// 256 thr / 4 waves; wave = m-quarter, full c=128, n=32. Main loop: K register
// ping-pong (1 iter ahead), V single-buffer (loaded post-consumption, hidden by
// next S phase). Zero LDS / barriers until the end reduction.
// ---------------------------------------------------------------------------
#define LOADK(KF, TILE) { \
    const unsigned short* kp_ = kbase + (size_t)(TILE) * 16384; \
    _Pragma("unroll") \
    for (int mi_ = 0; mi_ < 2; ++mi_) \
        _Pragma("unroll") \
        for (int kc_ = 0; kc_ < 4; ++kc_) \
            KF[mi_][kc_] = *(const v8bf*)(kp_ + (size_t)((mi_ * 4 + kc_) * 64) * 8); \
}

#define LOADV(TILE) { \
    const unsigned short* vp_ = vbase + (size_t)(TILE) * 16384; \
    _Pragma("unroll") \
    for (int cb_ = 0; cb_ < 8; ++cb_) \
        vf[cb_] = *(const v8bf*)(vp_ + (size_t)(cb_ * 256) * 8); \
}

#define COMPUTE(KF) { \
    v4f sacc[2][2]; \
    _Pragma("unroll") \
    for (int mi_ = 0; mi_ < 2; ++mi_) \
        _Pragma("unroll") \
        for (int ni_ = 0; ni_ < 2; ++ni_) sacc[mi_][ni_] = (v4f){0.f, 0.f, 0.f, 0.f}; \
    _Pragma("unroll") \
    for (int mi_ = 0; mi_ < 2; ++mi_) \
        _Pragma("unroll") \
        for (int kc_ = 0; kc_ < 4; ++kc_) \
            _Pragma("unroll") \
            for (int ni_ = 0; ni_ < 2; ++ni_) \
                sacc[mi_][ni_] = __builtin_amdgcn_mfma_f32_16x16x32_bf16( \
                    KF[mi_][kc_], qf[ni_][kc_], sacc[mi_][ni_], 0, 0, 0); \
    unsigned pk_[2][2][2]; \
    _Pragma("unroll") \
    for (int mi_ = 0; mi_ < 2; ++mi_) \
        _Pragma("unroll") \
        for (int ni_ = 0; ni_ < 2; ++ni_) { \
            float e0 = __expf(sacc[mi_][ni_][0]), e1 = __expf(sacc[mi_][ni_][1]); \
            float e2 = __expf(sacc[mi_][ni_][2]), e3 = __expf(sacc[mi_][ni_][3]); \
            lpart[ni_] += (e0 + e1) + (e2 + e3); \
            pk_[mi_][ni_][0] = __builtin_amdgcn_perm(fbits(e1), fbits(e0), 0x07060302); \
            pk_[mi_][ni_][1] = __builtin_amdgcn_perm(fbits(e3), fbits(e2), 0x07060302); \
        } \
    v8bf pf[2]; \
    _Pragma("unroll") \
    for (int ni_ = 0; ni_ < 2; ++ni_) { \
        unsigned sLo = (quad < 2) ? pk_[0][ni_][0] : pk_[1][ni_][0]; \
        unsigned sHi = (quad < 2) ? pk_[0][ni_][1] : pk_[1][ni_][1]; \
        union { unsigned u[4]; v8bf v; } pu; \
        pu.u[0] = (unsigned)__builtin_amdgcn_ds_bpermute(la, (int)sLo); \
        pu.u[1] = (unsigned)__builtin_amdgcn_ds_bpermute(la, (int)sHi); \
        pu.u[2] = (unsigned)__builtin_amdgcn_ds_bpermute(lb, (int)sLo); \
        pu.u[3] = (unsigned)__builtin_amdgcn_ds_bpermute(lb, (int)sHi); \
        pf[ni_] = pu.v; \
    } \
    _Pragma("unroll") \
    for (int cb_ = 0; cb_ < 8; ++cb_) \
        _Pragma("unroll") \
        for (int ni_ = 0; ni_ < 2; ++ni_) \
            oacc[cb_][ni_] = __builtin_amdgcn_mfma_f32_16x16x32_bf16( \
                vf[cb_], pf[ni_], oacc[cb_][ni_], 0, 0, 0); \
}

__global__ __launch_bounds__(256, 2) void attn_kernel(
    const unsigned short* __restrict__ qf_ws, const unsigned short* __restrict__ kt,
    const unsigned short* __restrict__ vt, const float* __restrict__ x,
    const float* __restrict__ gamma, float* __restrict__ out)
{
    __shared__ float red[32 * 132];   // O reduction scratch [n][c] (+pad)
    __shared__ float l_s[4][32];

    const int bid = blockIdx.x;
    const int bb  = bid & 7;
    const int s   = bid >> 3;        // n-strip 0..127 (32 rows each)
    const int n0  = s * 32;
    const int tid = threadIdx.x;
    const int w    = tid >> 6;       // wave = m-quarter owner
    const int lane = tid & 63;
    const int quad = lane >> 4;
    const int l16  = lane & 15;

    // ---- Q fragments (n=32 strip): 32 VGPR, iteration-invariant
    v8bf qf[2][4];
    {
        const unsigned short* qb = qf_ws + ((size_t)(bb * 128 + s)) * 4096;
        #pragma unroll
        for (int ni = 0; ni < 2; ++ni)
            #pragma unroll
            for (int kc = 0; kc < 4; ++kc)
                qf[ni][kc] = *(const v8bf*)(qb + ((size_t)(ni * 4 + kc) * 64 + lane) * 8);
    }

    v4f oacc[8][2];  // 64 regs: [cb][ni] partial O over this wave's 32-m subset
    #pragma unroll
    for (int i = 0; i < 8; ++i)
        #pragma unroll
        for (int j = 0; j < 2; ++j)
            oacc[i][j] = (v4f){0.f, 0.f, 0.f, 0.f};
    float lpart[2] = {0.f, 0.f};

    const int la = ((((quad & 1) << 1) << 4) + l16) << 2;  // bpermute byte idx
    const int lb = la + 64;

    const unsigned short* kbase = kt + ((size_t)(bb * 32)) * 16384 + ((size_t)(w * 8) * 64 + lane) * 8;
    const unsigned short* vbase = vt + ((size_t)(bb * 32)) * 16384 + ((size_t)(w * 64 + lane)) * 8;

    v8bf kfA[2][4], kfB[2][4], vf[8];

    LOADK(kfA, 0)
    LOADV(0)

    for (int it = 0; it < 32; it += 2) {
        LOADK(kfB, it + 1)
        COMPUTE(kfA)                 // consumes vf(it); K(it+1) in flight
        LOADV(it + 1)                // V for next compute, hidden by its S phase
        LOADK(kfA, (it + 2) & 31)
        COMPUTE(kfB)                 // consumes vf(it+1)
        LOADV((it + 2) & 31)
    }

    // ---- softmax denominators (per-wave partials over its 32-m subset)
    #pragma unroll
    for (int ni = 0; ni < 2; ++ni) {
        float r = lpart[ni];
        r += __shfl_xor(r, 16);
        r += __shfl_xor(r, 32);
        if (lane < 16) l_s[w][ni * 16 + lane] = r;
    }

    // ---- O reduction across the 4 m-quarter waves
    for (int rw = 0; rw < 4; ++rw) {
        if (w == rw) {
            #pragma unroll
            for (int cb = 0; cb < 8; ++cb)
                #pragma unroll
                for (int ni = 0; ni < 2; ++ni) {
                    float* p = &red[(ni * 16 + l16) * 132 + cb * 16 + quad * 4];
                    if (rw == 0) *(v4f*)p = oacc[cb][ni];
                    else {
                        v4f tv = *(const v4f*)p;
                        tv += oacc[cb][ni];
                        *(v4f*)p = tv;
                    }
                }
        }
        __syncthreads();
    }

    // ---- epilogue: out = gamma * O / l + x  (thread: n = tid&31, c-group = tid>>5)
    const float g = gamma[0];
    const int   n = tid & 31;
    const int  cg = tid >> 5;        // 0..7
    const float li = 1.0f / (((l_s[0][n] + l_s[1][n]) + (l_s[2][n] + l_s[3][n])));
    #pragma unroll
    for (int j = 0; j < 16; ++j) {
        const int c = cg * 16 + j;
        const size_t idx = ((size_t)(bb * C_ + c)) * N_ + n0 + n;
        out[idx] = g * red[n * 132 + c] * li + x[idx];
    }
}

// ---------------------------------------------------------------------------
extern "C" void kernel_launch(void* const* d_in, const int* in_sizes, int n_in,
                              void* d_out, int out_size, void* d_ws, size_t ws_size,
                              hipStream_t stream)
{
    (void)in_sizes; (void)n_in; (void)out_size; (void)ws_size;
    const float* x     = (const float*)d_in[0];
    const float* dw_q  = (const float*)d_in[1];
    const float* pw_q  = (const float*)d_in[2];
    const float* dw_k  = (const float*)d_in[3];
    const float* pw_k  = (const float*)d_in[4];
    const float* dw_v  = (const float*)d_in[5];
    const float* pw_v  = (const float*)d_in[6];
    const float* gamma = (const float*)d_in[7];
    float* out = (float*)d_out;

    unsigned short* qf_ws = (unsigned short*)d_ws;                  // 8 MB
    unsigned short* kt    = qf_ws + (size_t)B_ * N_ * C_;           // 8 MB
    unsigned short* vt    = kt    + (size_t)B_ * N_ * C_;           // 8 MB

    proj_kernel<<<dim3(768), dim3(256), 0, stream>>>(
        x, dw_q, pw_q, dw_k, pw_k, dw_v, pw_v, qf_ws, kt, vt);
    attn_kernel<<<dim3(1024), dim3(256), 0, stream>>>(
        qf_ws, kt, vt, x, gamma, out);
}